// Round 6
// baseline (8710.867 us; speedup 1.0000x reference)
//
#include <hip/hip_runtime.h>
#include <math.h>

#define TPB 512
#define NWG 512   // 64 groups x 8 WGs, 2 WG/CU (16 waves/CU)

// Cross-WG traffic: agent-scope relaxed atomics (coherence point, no stale-L2).
// Ordering: gbar's __syncthreads drains vmcnt before the arrive-add.
// ALL cross-WG data goes through g_ld/g_st; weight matrices are read-only
// kernel inputs (plain cached reads are safe and L2-resident by design).
__device__ __forceinline__ float g_ld(const float* p){
    return __hip_atomic_load(p, __ATOMIC_RELAXED, __HIP_MEMORY_SCOPE_AGENT);
}
__device__ __forceinline__ void g_st(float* p, float v){
    __hip_atomic_store(p, v, __ATOMIC_RELAXED, __HIP_MEMORY_SCOPE_AGENT);
}
__device__ __forceinline__ float sigm(float x){ return 1.f/(1.f+expf(-x)); }

__global__ __launch_bounds__(TPB, 4) void decoder_persistent(
    const float* __restrict__ xs_h, const float* __restrict__ ys_e,
    const float* __restrict__ xs_mask, const float* __restrict__ ys_mask,
    const float* __restrict__ W_sinit, const float* __restrict__ b_sinit,
    const float* __restrict__ W_keys,
    const float* __restrict__ Wx_cell, const float* __restrict__ bx_cell,
    const float* __restrict__ gx_cell, const float* __restrict__ Wh_cell,
    const float* __restrict__ gh_cell,
    const float* __restrict__ Wx_cond, const float* __restrict__ bx_cond,
    const float* __restrict__ gx_cond, const float* __restrict__ Wh_cond,
    const float* __restrict__ gh_cond,
    const float* __restrict__ Wq, const float* __restrict__ bq,
    const float* __restrict__ V_att, const float* __restrict__ Wo,
    const float* __restrict__ bo, const float* __restrict__ Wy,
    const float* __restrict__ by, const float* __restrict__ Wc,
    const float* __restrict__ bc, const float* __restrict__ Wsm,
    const float* __restrict__ bs,
    float* __restrict__ out, float* __restrict__ ws)
{
    const int w    = blockIdx.x;
    const int tid  = threadIdx.x;
    const int lane = tid & 63, wv = tid >> 6;   // 8 waves
    const int i    = w & 7;          // column slice (== XCD under %8 mapping; perf-only)
    const int grp  = w >> 3;         // group 0..63
    const int b    = grp;            // this group's single batch row

    // ---------------- workspace layout (floats), total ~11.08M = 44.3 MB ----------------
    unsigned* cntg = (unsigned*)ws + (size_t)grp * 16;   // group barrier ctr (64B padded)
    float* AXn  = ws + 1024;                             // [64][64][1536] LN'd x-branch
    float* uhP  = AXn  + (size_t)64*64*1536;             // [512][8][512] WG-private
    float* YWbP = uhP  + (size_t)512*8*512;              // [512][64][64] WG-private
    float* PB   = YWbP + (size_t)512*64*64;              // [64][9216] per-group block
    float* pb     = PB + (size_t)grp * 9216;
    float* tmpH_  = pb;            // [1536]
    float* tmpHC_ = pb + 1536;     // [1536]
    float* tmpXC_ = pb + 3072;     // [1536]
    float* qb_    = pb + 4608;     // [512]
    float* e_     = pb + 5120;     // [64][8]
    float* ctx0_  = pb + 5632;     // [1024]
    float* ctx_   = pb + 6656;     // [1024]
    float* pool_  = pb + 7680;     // [1024]
    float* s0_    = pb + 8704;     // [512]

    // ---------------- LDS (~20 KB) ----------------
    __shared__ float sal[512];     // carry s_t (identical in all 8 WGs)
    __shared__ float sbl[512];     // cell-GRU "state"
    __shared__ float al[64];       // alpha for head i
    __shared__ float outcl[64];    // ctx@Wc slice
    __shared__ float xml[64];      // xs_mask row
    __shared__ float red[8][12];
    __shared__ float red2[12];
    __shared__ float arena[1024 + 2560];   // xv[1024] + comb[2560]
    float* xv   = arena;
    float* comb = arena + 1024;

    unsigned gen = 0;
    auto gbar = [&](){
        __syncthreads();             // vmcnt(0) drain = release for all g_st
        ++gen;
        if (tid == 0){
            __hip_atomic_fetch_add(cntg, 1u, __ATOMIC_RELAXED, __HIP_MEMORY_SCOPE_AGENT);
            while (__hip_atomic_load(cntg, __ATOMIC_RELAXED, __HIP_MEMORY_SCOPE_AGENT) < 8u*gen)
                __builtin_amdgcn_s_sleep(2);
        }
        asm volatile("" ::: "memory");
        __syncthreads();
    };

    auto breduce = [&](float* v, int nv){
        for (int n = 0; n < nv; ++n){
            float x = v[n];
            #pragma unroll
            for (int o = 32; o; o >>= 1) x += __shfl_xor(x, o);
            v[n] = x;
        }
        if (lane == 0) for (int n = 0; n < nv; ++n) red[wv][n] = v[n];
        __syncthreads();
        if (tid < nv){ float s = 0.f; for (int q = 0; q < 8; ++q) s += red[q][tid]; red2[tid] = s; }
        __syncthreads();
        for (int n = 0; n < nv; ++n) v[n] = red2[n];
    };

    // dual-matrix sliced GEMV, single x row, 256 output cols, K-split 8.
    // cg<CGA -> Wa (cols ca+4cg), else Wb (cols cb+4(cg-CGA)). Result valid for
    // tid<256 (c=tid). float4 weight loads, 8-deep batches.
    auto gemv1 = [&](const float* Wa, int lda, int ca,
                     const float* Wb, int ldb, int cb, int CGA,
                     const float* x, int K)->float{
        int cg = tid & 63, kq = tid >> 6;
        const float* W; int ld, col;
        if (cg < CGA){ W = Wa; ld = lda; col = ca + 4*cg; }
        else         { W = Wb; ld = ldb; col = cb + 4*(cg - CGA); }
        int Kq = K >> 3;
        const float* wp = W + (size_t)(kq*Kq)*ld + col;
        const float* xa = x + kq*Kq;
        float a0=0,a1=0,a2=0,a3=0;
        for (int kk = 0; kk < Kq; kk += 8){
            float4 wr[8];
            #pragma unroll
            for (int u = 0; u < 8; ++u) wr[u] = *(const float4*)(wp + (size_t)(kk+u)*ld);
            #pragma unroll
            for (int u = 0; u < 8; ++u){
                float xA = xa[kk+u];
                a0 = fmaf(xA, wr[u].x, a0); a1 = fmaf(xA, wr[u].y, a1);
                a2 = fmaf(xA, wr[u].z, a2); a3 = fmaf(xA, wr[u].w, a3);
            }
        }
        float* cp = comb + tid*5;
        cp[0]=a0; cp[1]=a1; cp[2]=a2; cp[3]=a3;
        __syncthreads();
        float s = 0.f;
        if (tid < 256){
            int c = tid, cgq = c >> 2, j = c & 3;
            #pragma unroll
            for (int q = 0; q < 8; ++q) s += comb[(q*64 + cgq)*5 + j];
        }
        __syncthreads();
        return s;
    };

    // ======================= precompute =======================
    if (tid < 64) xml[tid] = xs_mask[(size_t)b*64 + tid];
    __syncthreads();

    // ---- uh (private): 8 jobs (l = i*8+j), 512 cols, K=1024; W_keys read once ----
    {
        int c4 = tid & 127, kq = tid >> 7;           // 4 kq x 256 k
        unsigned base[8];
        #pragma unroll
        for (int j = 0; j < 8; ++j)
            base[j] = (unsigned)((b*64 + i*8 + j)*1024 + kq*256);
        const float* wp = W_keys + (size_t)(kq*256)*512 + 4*c4;
        float4 acc[8];
        #pragma unroll
        for (int j = 0; j < 8; ++j) acc[j] = make_float4(0.f,0.f,0.f,0.f);
        for (int kk = 0; kk < 256; ++kk){
            float4 wr = *(const float4*)(wp + (size_t)kk*512);
            #pragma unroll
            for (int j = 0; j < 8; ++j){
                float xr = xs_h[base[j] + kk];
                acc[j].x = fmaf(xr, wr.x, acc[j].x); acc[j].y = fmaf(xr, wr.y, acc[j].y);
                acc[j].z = fmaf(xr, wr.z, acc[j].z); acc[j].w = fmaf(xr, wr.w, acc[j].w);
            }
        }
        for (int r = 0; r < 8; ++r){
            float* cp = comb + tid*5;
            cp[0]=acc[r].x; cp[1]=acc[r].y; cp[2]=acc[r].z; cp[3]=acc[r].w;
            __syncthreads();
            int c = tid; float s = 0.f;
            #pragma unroll
            for (int q = 0; q < 4; ++q) s += comb[(q*128 + (c>>2))*5 + (c&3)];
            uhP[((size_t)w*8 + r)*512 + c] = s;
            __syncthreads();
        }
    }

    // ---- AXn (published to group): 8 rows (t = i*8+j), LN(ys_e@Wx_cell)*gx+bx ----
    // LN variance is TWO-PASS (mu first, then mean((v-mu)^2)) to match reference
    // numerics; one-pass E[x^2]-mu^2 cancels catastrophically in fp32 (round-3 lesson).
    for (int g = 0; g < 3; ++g){
        int c4 = tid & 127, kq = tid >> 7;           // 4 kq x 128 k
        unsigned base[8];
        #pragma unroll
        for (int j = 0; j < 8; ++j)
            base[j] = (unsigned)((b*64 + i*8 + j)*512 + kq*128);
        const float* wp = Wx_cell + (size_t)(kq*128)*1536 + g*512 + 4*c4;
        float4 acc[8];
        #pragma unroll
        for (int j = 0; j < 8; ++j) acc[j] = make_float4(0.f,0.f,0.f,0.f);
        for (int kk = 0; kk < 128; ++kk){
            float4 wr = *(const float4*)(wp + (size_t)kk*1536);
            #pragma unroll
            for (int j = 0; j < 8; ++j){
                float xr = ys_e[base[j] + kk];
                acc[j].x = fmaf(xr, wr.x, acc[j].x); acc[j].y = fmaf(xr, wr.y, acc[j].y);
                acc[j].z = fmaf(xr, wr.z, acc[j].z); acc[j].w = fmaf(xr, wr.w, acc[j].w);
            }
        }
        for (int r = 0; r < 8; ++r){
            float* cp = comb + tid*5;
            cp[0]=acc[r].x; cp[1]=acc[r].y; cp[2]=acc[r].z; cp[3]=acc[r].w;
            __syncthreads();
            int c = tid; float val = 0.f;
            #pragma unroll
            for (int q = 0; q < 4; ++q) val += comb[(q*128 + (c>>2))*5 + (c&3)];
            float s1[1] = { val };
            breduce(s1, 1);
            float mu = s1[0]*(1.f/512.f);
            float d = val - mu;
            float s2[1] = { d*d };
            breduce(s2, 1);
            float rstd = rsqrtf(s2[0]*(1.f/512.f) + 1e-5f);
            int t = i*8 + r, cg2 = g*512 + c;
            g_st(&AXn[((size_t)b*64 + t)*1536 + cg2],
                 d*rstd*gx_cell[cg2] + bx_cell[cg2]);
            __syncthreads();
        }
    }

    // ---- YWb (private): 64 rows (t) in 4 chunks of 16, 64-col slice ----
    for (int cc = 0; cc < 4; ++cc){
        int c4 = tid & 15, kq = tid >> 4;            // 32 kq x 16 k
        unsigned base[16];
        #pragma unroll
        for (int r = 0; r < 16; ++r)
            base[r] = (unsigned)((b*64 + cc*16 + r)*512 + kq*16);
        const float* wp = Wy + (size_t)(kq*16)*512 + i*64 + 4*c4;
        float4 acc[16];
        #pragma unroll
        for (int r = 0; r < 16; ++r) acc[r] = make_float4(0.f,0.f,0.f,0.f);
        for (int kk = 0; kk < 16; ++kk){
            float4 wr = *(const float4*)(wp + (size_t)kk*512);
            #pragma unroll
            for (int r = 0; r < 16; ++r){
                float xr = ys_e[base[r] + kk];
                acc[r].x = fmaf(xr, wr.x, acc[r].x); acc[r].y = fmaf(xr, wr.y, acc[r].y);
                acc[r].z = fmaf(xr, wr.z, acc[r].z); acc[r].w = fmaf(xr, wr.w, acc[r].w);
            }
        }
        for (int r = 0; r < 16; ++r){
            float* cp = comb + tid*5;
            cp[0]=acc[r].x; cp[1]=acc[r].y; cp[2]=acc[r].z; cp[3]=acc[r].w;
            __syncthreads();
            if (tid < 64){
                int c = tid; float s = 0.f;
                #pragma unroll
                for (int q = 0; q < 32; ++q) s += comb[(q*16 + (c>>2))*5 + (c&3)];
                YWbP[((size_t)w*64 + cc*16 + r)*64 + c] = s + by[i*64 + c];
            }
            __syncthreads();
        }
    }

    // ---- pooled slice ----
    if (tid < 128){
        int c = i*128 + tid;
        float msum = 0.f;
        for (int l = 0; l < 64; ++l) msum += xml[l];
        float a = 0.f;
        for (int l = 0; l < 64; ++l)
            a += xs_h[((size_t)b*64 + l)*1024 + c] * xml[l];
        g_st(&pool_[c], a / msum);
    }
    gbar();   // publish AXn + pooled (group-local)

    // ---- s0 = tanh(pooled @ W_sinit + b) ----
    for (int k = tid; k < 1024; k += TPB) xv[k] = g_ld(&pool_[k]);
    __syncthreads();
    {
        int c4 = tid & 15, kq = tid >> 4;            // 32 kq x 32 k
        const float* wp = W_sinit + (size_t)(kq*32)*512 + i*64 + 4*c4;
        float4 A = make_float4(0.f,0.f,0.f,0.f);
        for (int kk = 0; kk < 32; ++kk){
            float4 wr = *(const float4*)(wp + (size_t)kk*512);
            float xA = xv[kq*32 + kk];
            A.x = fmaf(xA, wr.x, A.x); A.y = fmaf(xA, wr.y, A.y);
            A.z = fmaf(xA, wr.z, A.z); A.w = fmaf(xA, wr.w, A.w);
        }
        float* cp = comb + tid*5;
        cp[0]=A.x; cp[1]=A.y; cp[2]=A.z; cp[3]=A.w;
        __syncthreads();
        if (tid < 64){
            int c = tid; float s = 0.f;
            #pragma unroll
            for (int q = 0; q < 32; ++q) s += comb[(q*16 + (c>>2))*5 + (c&3)];
            g_st(&s0_[i*64 + c], tanhf(s + b_sinit[i*64 + c]));
        }
        __syncthreads();
    }
    gbar();
    sal[tid] = g_ld(&s0_[tid]);
    __syncthreads();

    // ---- tmpH for t=0 ----
    {
        float r0 = gemv1(Wsm, 512, i*64, Wh_cell, 1536, i*192, 16, sal, 512);
        if (tid < 256){
            int c = tid;
            if (c >= 64) g_st(&tmpH_[i*192 + (c - 64)], r0);
        }
    }
    gbar();

    // ======================= sequential scan =======================
    for (int t = 0; t < 64; ++t){
        const float ym = ys_mask[(size_t)b*64 + t];

        // ---- phase A: cell-GRU (redundant, two-pass LN) + qb/tmpHC slice ----
        {
            float th[3], ax[3], st[3];
            #pragma unroll
            for (int g = 0; g < 3; ++g){
                th[g] = g_ld(&tmpH_[g*512 + tid]);
                ax[g] = g_ld(&AXn[((size_t)b*64 + t)*1536 + g*512 + tid]);
                st[g] = th[g];
            }
            breduce(st, 3);
            float dv[3], st2[3];
            #pragma unroll
            for (int g = 0; g < 3; ++g){
                float mu = st[g]*(1.f/512.f);
                dv[g] = th[g] - mu;
                st2[g] = dv[g]*dv[g];
            }
            breduce(st2, 3);
            float ah[3];
            #pragma unroll
            for (int g = 0; g < 3; ++g)
                ah[g] = dv[g]*rsqrtf(st2[g]*(1.f/512.f) + 1e-5f)*gh_cell[g*512 + tid];
            float h  = sal[tid];
            float r  = sigm(ax[0] + ah[0]);
            float z  = sigm(ax[1] + ah[1]);
            float hc = tanhf(ax[2] + r*ah[2]);
            float hn = (1.f - z)*h + z*hc;
            sbl[tid] = ym*hn + (1.f - ym)*h;
        }
        __syncthreads();
        {
            float ra = gemv1(Wq, 512, i*64, Wh_cond, 1536, i*192, 16, sbl, 512);
            if (tid < 256){
                int c = tid;
                if (c < 64){ int col = i*64 + c; g_st(&qb_[col], ra + bq[col]); }
                else g_st(&tmpHC_[i*192 + (c - 64)], ra);
            }
        }
        gbar();  // A

        // ---- phase B: attention scores, one l job per wave ----
        xv[tid] = g_ld(&qb_[tid]);
        __syncthreads();
        {
            int l = i*8 + wv;
            float acc[8] = {0.f,0.f,0.f,0.f,0.f,0.f,0.f,0.f};
            #pragma unroll
            for (int u = 0; u < 8; ++u){
                int d = u*64 + lane;
                float hid = tanhf(uhP[((size_t)w*8 + wv)*512 + d] + xv[d]);
                float4 va = *(const float4*)&V_att[(size_t)d*8];
                float4 vb = *(const float4*)&V_att[(size_t)d*8 + 4];
                acc[0] = fmaf(hid, va.x, acc[0]); acc[1] = fmaf(hid, va.y, acc[1]);
                acc[2] = fmaf(hid, va.z, acc[2]); acc[3] = fmaf(hid, va.w, acc[3]);
                acc[4] = fmaf(hid, vb.x, acc[4]); acc[5] = fmaf(hid, vb.y, acc[5]);
                acc[6] = fmaf(hid, vb.z, acc[6]); acc[7] = fmaf(hid, vb.w, acc[7]);
            }
            #pragma unroll
            for (int h = 0; h < 8; ++h)
                #pragma unroll
                for (int o = 32; o; o >>= 1) acc[h] += __shfl_xor(acc[h], o);
            if (lane == 0){
                float mk = xml[l];
                #pragma unroll
                for (int h = 0; h < 8; ++h)
                    g_st(&e_[(size_t)l*8 + h], (mk > 0.f) ? acc[h] : -1e9f);
            }
        }
        gbar();  // B

        // ---- phase C: softmax (head i) + ctx0 slice ----
        if (wv == 0){
            float v = g_ld(&e_[(size_t)lane*8 + i]);
            float mx = v;
            #pragma unroll
            for (int o = 32; o; o >>= 1) mx = fmaxf(mx, __shfl_xor(mx, o));
            float ex = expf(v - mx);
            float ss = ex;
            #pragma unroll
            for (int o = 32; o; o >>= 1) ss += __shfl_xor(ss, o);
            al[lane] = ex / ss;
        }
        __syncthreads();
        {
            int kq = tid >> 5, cg = tid & 31;        // 16 kq x 4 l, 32 cg x 4 cols
            int c0 = i*128 + 4*cg;
            float4 a4 = make_float4(0.f,0.f,0.f,0.f);
            #pragma unroll
            for (int u = 0; u < 4; ++u){
                int l = kq*4 + u;
                float a = al[l];
                float4 xw = *(const float4*)&xs_h[((size_t)b*64 + l)*1024 + c0];
                a4.x = fmaf(a, xw.x, a4.x); a4.y = fmaf(a, xw.y, a4.y);
                a4.z = fmaf(a, xw.z, a4.z); a4.w = fmaf(a, xw.w, a4.w);
            }
            float* cp = comb + tid*5;
            cp[0]=a4.x; cp[1]=a4.y; cp[2]=a4.z; cp[3]=a4.w;
            __syncthreads();
            if (tid < 128){
                int c = tid; float s = 0.f;
                #pragma unroll
                for (int q = 0; q < 16; ++q) s += comb[(q*32 + (c>>2))*5 + (c&3)];
                g_st(&ctx0_[i*128 + c], s);
            }
            __syncthreads();
        }
        gbar();  // C

        // ---- phase D: ctx = (ctx0 @ Wo + bo) * ym  (direct Wo, K-split 16) ----
        for (int k = tid; k < 1024; k += TPB) xv[k] = g_ld(&ctx0_[k]);
        __syncthreads();
        {
            int kq = tid >> 5, cg = tid & 31;        // 16 kq x 64 k, 32 cg x 4 cols
            int c0 = i*128 + 4*cg;
            const float* wp = Wo + (size_t)(kq*64)*1024 + c0;
            const float* xa = xv + kq*64;
            float a0=0,a1=0,a2=0,a3=0;
            for (int kk = 0; kk < 64; kk += 8){
                float4 wr[8];
                #pragma unroll
                for (int u = 0; u < 8; ++u) wr[u] = *(const float4*)(wp + (size_t)(kk+u)*1024);
                #pragma unroll
                for (int u = 0; u < 8; ++u){
                    float xA = xa[kk+u];
                    a0 = fmaf(xA, wr[u].x, a0); a1 = fmaf(xA, wr[u].y, a1);
                    a2 = fmaf(xA, wr[u].z, a2); a3 = fmaf(xA, wr[u].w, a3);
                }
            }
            float* cp = comb + tid*5;
            cp[0]=a0; cp[1]=a1; cp[2]=a2; cp[3]=a3;
            __syncthreads();
            if (tid < 128){
                int c = tid; float s = 0.f;
                #pragma unroll
                for (int q = 0; q < 16; ++q) s += comb[(q*32 + (c>>2))*5 + (c&3)];
                g_st(&ctx_[i*128 + c], (s + bo[i*128 + c]) * ym);
            }
            __syncthreads();
        }
        gbar();  // D

        // ---- phase E: tmpXC (Wx_cond) + outc (Wc) from ctx ----
        for (int k = tid; k < 1024; k += TPB) xv[k] = g_ld(&ctx_[k]);
        __syncthreads();
        {
            float re = gemv1(Wx_cond, 1536, i*192, Wc, 512, i*64, 48, xv, 1024);
            if (tid < 256){
                int c = tid;
                if (c < 192) g_st(&tmpXC_[i*192 + c], re);
                else         outcl[c - 192] = re;
            }
        }
        gbar();  // E

        // ---- phase F: cond-GRU (redundant, two-pass LN) + out + tmpH(t+1) ----
        {
            float tx[3], th[3], st[6];
            #pragma unroll
            for (int g = 0; g < 3; ++g){
                tx[g] = g_ld(&tmpXC_[g*512 + tid]);
                th[g] = g_ld(&tmpHC_[g*512 + tid]);
                st[g]     = tx[g];
                st[3 + g] = th[g];
            }
            breduce(st, 6);
            float dx[3], dh[3], st2[6];
            #pragma unroll
            for (int g = 0; g < 3; ++g){
                float mux = st[g]*(1.f/512.f);
                float muh = st[3 + g]*(1.f/512.f);
                dx[g] = tx[g] - mux;
                dh[g] = th[g] - muh;
                st2[g]     = dx[g]*dx[g];
                st2[3 + g] = dh[g]*dh[g];
            }
            breduce(st2, 6);
            float axc[3], ahc[3];
            #pragma unroll
            for (int g = 0; g < 3; ++g){
                int c2 = g*512 + tid;
                axc[g] = dx[g]*rsqrtf(st2[g]*(1.f/512.f) + 1e-5f)*gx_cond[c2] + bx_cond[c2];
                ahc[g] = dh[g]*rsqrtf(st2[3+g]*(1.f/512.f) + 1e-5f)*gh_cond[c2];
            }
            float h  = sbl[tid];
            float r  = sigm(axc[0] + ahc[0]);
            float z  = sigm(axc[1] + ahc[1]);
            float hc = tanhf(axc[2] + r*ahc[2]);
            float hn = (1.f - z)*h + z*hc;
            float snew = ym*hn + (1.f - ym)*h;
            __syncthreads();
            sal[tid] = snew;
        }
        __syncthreads();
        {
            float rf = gemv1(Wsm, 512, i*64, Wh_cell, 1536, i*192, 16, sal, 512);
            if (tid < 256){
                int c = tid;
                if (c < 64){
                    int col = i*64 + c;
                    float v = rf + YWbP[((size_t)w*64 + t)*64 + c]
                            + outcl[c] + bc[col] + bs[col];
                    out[((size_t)b*64 + t)*512 + col] = tanhf(v)*ym;
                } else {
                    g_st(&tmpH_[i*192 + (c - 64)], rf);
                }
            }
        }
        gbar();  // F
    }
}

// ---------------------------------------------------------------------------
extern "C" void kernel_launch(void* const* d_in, const int* in_sizes, int n_in,
                              void* d_out, int out_size, void* d_ws, size_t ws_size,
                              hipStream_t stream)
{
    // re-zero barrier counters on every graph replay (64 groups x 64B)
    hipMemsetAsync(d_ws, 0, 4096, stream);

    decoder_persistent<<<dim3(NWG), dim3(TPB), 0, stream>>>(
        (const float*)d_in[0],  (const float*)d_in[1],  (const float*)d_in[2],
        (const float*)d_in[3],  (const float*)d_in[4],  (const float*)d_in[5],
        (const float*)d_in[6],  (const float*)d_in[7],  (const float*)d_in[8],
        (const float*)d_in[9],  (const float*)d_in[10], (const float*)d_in[11],
        (const float*)d_in[12], (const float*)d_in[13], (const float*)d_in[14],
        (const float*)d_in[15], (const float*)d_in[16], (const float*)d_in[17],
        (const float*)d_in[18], (const float*)d_in[19], (const float*)d_in[20],
        (const float*)d_in[21], (const float*)d_in[22], (const float*)d_in[23],
        (const float*)d_in[24], (const float*)d_in[25], (const float*)d_in[26],
        (const float*)d_in[27],
        (float*)d_out, (float*)d_ws);
}